// Round 18
// baseline (910.362 us; speedup 1.0000x reference)
//
#include <hip/hip_runtime.h>
#include <hip/hip_bf16.h>

typedef __attribute__((ext_vector_type(8))) __bf16 bf16x8;
typedef __attribute__((ext_vector_type(4))) float f32x4;

#define MFMA(a,b,c) __builtin_amdgcn_mfma_f32_16x16x32_bf16((a),(b),(c),0,0,0)

__device__ __forceinline__ bf16x8 cvt8(float4 a, float4 b){
  bf16x8 r;
  r[0]=(__bf16)a.x; r[1]=(__bf16)a.y; r[2]=(__bf16)a.z; r[3]=(__bf16)a.w;
  r[4]=(__bf16)b.x; r[5]=(__bf16)b.y; r[6]=(__bf16)b.z; r[7]=(__bf16)b.w;
  return r;
}

// ---- fused setup: blocks 0-15 pack weights (transposed A-operand layout),
// blocks 16+ zero the counter/stat region.
__global__ void setup_k(const float* __restrict__ W_sg, const float* __restrict__ W_dg,
                        const float* __restrict__ W_eg, const float* __restrict__ W_su,
                        const float* __restrict__ W_du,
                        bf16x8* __restrict__ Wq,
                        int4* __restrict__ zp, int nz4){
  if (blockIdx.x < 16){
    int tid = blockIdx.x*256 + threadIdx.x;
    if (tid >= 2560) return;
    int lane = tid & 63, g = lane>>4, c = lane&15;
    int frag = (tid>>6)&7, m = tid>>9;
    const float* Ws[5] = {W_eg, W_sg, W_dg, W_du, W_su};
    const float* W = Ws[m];
    int mt = frag>>1, kh = frag&1;
    bf16x8 v;
    #pragma unroll
    for (int j=0;j<8;j++) v[j] = (__bf16)W[(kh*32+g*8+j)*64 + mt*16 + c];
    Wq[tid] = v;
  } else {
    int i = (blockIdx.x-16)*256 + threadIdx.x, st = (gridDim.x-16)*256;
    for (; i<nz4; i+=st) zp[i] = make_int4(0,0,0,0);
  }
}

// ---- fused: blocks [0,nxf): node transforms -> es16/ed16/bh16 (bf16, no bias)
// + A_src (f32, no bias); blocks [nxf,+): dst histogram.
__global__ __launch_bounds__(256) void xform_hist_k(
    const float* __restrict__ nf, const bf16x8* __restrict__ Wq,
    __bf16* __restrict__ es16, __bf16* __restrict__ ed16,
    __bf16* __restrict__ bh16, float* __restrict__ A_src, int ntiles, int nxf,
    const int* __restrict__ dst, int* __restrict__ cnt, int E)
{
  if ((int)blockIdx.x < nxf){
    int lane = threadIdx.x & 63;
    int gw = blockIdx.x*4 + (threadIdx.x>>6);
    if (gw >= ntiles) return;
    int g = lane>>4, c = lane&15;
    long base = (long)gw*16;
    const float* rp = nf + (base + c)*64 + g*8;
    float4 a0 = *(const float4*)rp,      a1 = *(const float4*)(rp+4);
    float4 a2 = *(const float4*)(rp+32), a3 = *(const float4*)(rp+36);
    bf16x8 B0 = cvt8(a0,a1), B1 = cvt8(a2,a3);
    __bf16* outs[3] = {es16, ed16, bh16};
    const int mats[3] = {1,2,3};           // sg, dg, du
    #pragma unroll
    for (int i=0;i<3;i++){
      #pragma unroll
      for (int mt=0;mt<4;mt++){
        f32x4 am = {0.f,0.f,0.f,0.f};
        am = MFMA(Wq[(mats[i]*8+mt*2+0)*64+lane], B0, am);
        am = MFMA(Wq[(mats[i]*8+mt*2+1)*64+lane], B1, am);
        union { __bf16 h[4]; uint2 u; } pk;
        #pragma unroll
        for (int e=0;e<4;e++) pk.h[e] = (__bf16)am[e];
        *(uint2*)(outs[i] + (base+c)*64 + mt*16 + 4*g) = pk.u;
      }
    }
    #pragma unroll
    for (int mt=0;mt<4;mt++){
      f32x4 am = {0.f,0.f,0.f,0.f};
      am = MFMA(Wq[(4*8+mt*2+0)*64+lane], B0, am);
      am = MFMA(Wq[(4*8+mt*2+1)*64+lane], B1, am);
      *(float4*)(A_src + (base+c)*64 + mt*16 + 4*g) =
        make_float4(am[0],am[1],am[2],am[3]);
    }
  } else {
    int nb = gridDim.x - nxf;
    int i = (blockIdx.x-nxf)*256 + threadIdx.x, st = nb*256;
    for (; i<E; i+=st) atomicAdd(&cnt[dst[i]], 1);
  }
}

__global__ __launch_bounds__(1024) void scan_k(const int* __restrict__ cnt,
                                               int* __restrict__ row, int Nn){
  __shared__ int part[1024];
  int t = threadIdx.x;
  int C = (Nn + 1023) >> 10;
  int lo = t*C;
  int hi = lo + C; if (hi > Nn) hi = Nn;
  int s = 0;
  for (int i=lo; i<hi; i++) s += cnt[i];
  part[t] = s;
  __syncthreads();
  for (int off=1; off<1024; off<<=1){
    int v = part[t];
    int u = (t>=off) ? part[t-off] : 0;
    __syncthreads();
    part[t] = v + u;
    __syncthreads();
  }
  int excl = (t==0) ? 0 : part[t-1];
  for (int i=lo; i<hi; i++){ row[i] = excl; excl += cnt[i]; }
  if (t==1023) row[Nn] = excl;
}

struct T2 {
  float4 e0,e1,e2,e3;
  bf16x8 bs0,bs1,bd0,bd1;
};

__device__ __forceinline__ T2 ld_t2(const float* __restrict__ ef,
                                    const __bf16* __restrict__ es16,
                                    const __bf16* __restrict__ ed16,
                                    long base, int c, int g, int sc, int dc){
  T2 t;
  const float* rpe = ef + (base+c)*64 + g*8;
  t.e0=*(const float4*)rpe;      t.e1=*(const float4*)(rpe+4);
  t.e2=*(const float4*)(rpe+32); t.e3=*(const float4*)(rpe+36);
  t.bs0 = *(const bf16x8*)(es16 + (long)sc*64 + g*8);
  t.bs1 = *(const bf16x8*)(es16 + (long)sc*64 + 32 + g*8);
  t.bd0 = *(const bf16x8*)(ed16 + (long)dc*64 + g*8);
  t.bd1 = *(const bf16x8*)(ed16 + (long)dc*64 + 32 + g*8);
  return t;
}

// ---- fused: blocks [0,NFILL) CSR fill; blocks [NFILL,+) phaseA.
// phaseA: eid-major, 2-deep pipeline, LDS-staged coalesced m16 stores,
// PLUS edge-BN stat accumulation (sum m, sum m^2) -> est.
#define NFILL 1024
__global__ __launch_bounds__(256) void fillA_k(
    const int* __restrict__ src, const int* __restrict__ dst,
    const int* __restrict__ rowp, int* __restrict__ cnt2,
    int2* __restrict__ pairs, int E,
    const float* __restrict__ ef,
    const __bf16* __restrict__ es16, const __bf16* __restrict__ ed16,
    const float* __restrict__ b_sg, const float* __restrict__ b_dg,
    const float* __restrict__ b_eg,
    const bf16x8* __restrict__ Wq,
    __bf16* __restrict__ m16, float* __restrict__ est, int ntiles)
{
  __shared__ bf16x8 wl[8*64];      // W_eg^T frags (8KB)
  __shared__ uint2 mst[4][256];    // per-wave m16 tile stage (8KB)
  __shared__ float sst2[128];      // block-level est stage
  if (blockIdx.x < NFILL){
    int i = blockIdx.x*256 + threadIdx.x, st = NFILL*256;
    for (; i<E; i+=st){
      int d = dst[i];
      int pos = rowp[d] + atomicAdd(&cnt2[d], 1);
      pairs[pos] = make_int2(i, src[i]);
    }
    return;
  }
  {
    int t = threadIdx.x;
    #pragma unroll
    for (int i=0;i<2;i++) wl[i*256+t] = Wq[i*256+t];   // eg frags 0-7
    if (t < 128) sst2[t] = 0.f;
  }
  __syncthreads();
  int lane = threadIdx.x & 63, g = lane>>4, c = lane&15;
  int wv = threadIdx.x>>6;
  bf16x8 I0, I1;
  #pragma unroll
  for (int j=0;j<8;j++){
    I0[j] = (g*8+j == c)      ? (__bf16)1.0f : (__bf16)0.0f;
    I1[j] = (g*8+j == 16 + c) ? (__bf16)1.0f : (__bf16)0.0f;
  }
  int gw = (blockIdx.x-NFILL)*4 + wv;
  int nw = (gridDim.x-NFILL)*4;
  float bias2[4][4], es1[4][4], es2[4][4];
  #pragma unroll
  for (int mt=0;mt<4;mt++)
    #pragma unroll
    for (int e=0;e<4;e++){
      int f = mt*16 + 4*g + e;
      bias2[mt][e] = b_sg[f] + b_dg[f] + b_eg[f];
      es1[mt][e] = 0.f; es2[mt][e] = 0.f;
    }
  if (gw < ntiles){
    int sc = src[(long)gw*16 + c], dc = dst[(long)gw*16 + c];
    T2 cur = ld_t2(ef, es16, ed16, (long)gw*16, c, g, sc, dc);
    int t1i = gw + nw;
    int sn = sc, dn = dc;
    if (t1i < ntiles){ sn = src[(long)t1i*16 + c]; dn = dst[(long)t1i*16 + c]; }
    int r_o = lane>>3;
    int u0_o = (lane&7)*2;
    for (int tt=gw; tt<ntiles; tt+=nw){
      int t1 = tt + nw;
      T2 nxt;
      if (t1 < ntiles) nxt = ld_t2(ef, es16, ed16, (long)t1*16, c, g, sn, dn);
      int t2 = t1 + nw;
      if (t2 < ntiles){ sn = src[(long)t2*16 + c]; dn = dst[(long)t2*16 + c]; }
      bf16x8 BE0=cvt8(cur.e0,cur.e1), BE1=cvt8(cur.e2,cur.e3);
      #pragma unroll
      for (int mt=0;mt<4;mt++){
        bf16x8 Is = (mt&1) ? I1 : I0;
        f32x4 am = {0.f,0.f,0.f,0.f};
        am = MFMA(wl[(mt*2+0)*64+lane], BE0, am);
        am = MFMA(wl[(mt*2+1)*64+lane], BE1, am);
        am = MFMA(Is, (mt>>1) ? cur.bs1 : cur.bs0, am);
        am = MFMA(Is, (mt>>1) ? cur.bd1 : cur.bd0, am);
        union { __bf16 h[4]; uint2 u; } pk;
        #pragma unroll
        for (int e=0;e<4;e++){
          float mv = am[e] + bias2[mt][e];
          es1[mt][e] += mv; es2[mt][e] += mv*mv;
          pk.h[e] = (__bf16)mv;
        }
        int u = mt*4 + g;
        mst[wv][c*16 + (u^c)] = pk.u;
      }
      char* tb = (char*)m16 + (size_t)tt*16*128;
      #pragma unroll
      for (int k=0;k<2;k++){
        int r = k*8 + r_o;
        uint2 a = mst[wv][r*16 + ( u0_o      ^ r)];
        uint2 b = mst[wv][r*16 + ((u0_o + 1) ^ r)];
        *(uint4*)(tb + k*1024 + lane*16) = make_uint4(a.x,a.y,b.x,b.y);
      }
      cur = nxt;
    }
  }
  // est flush: shfl-reduce over c-groups, LDS, then global atomics
  #pragma unroll
  for (int mt=0;mt<4;mt++)
    #pragma unroll
    for (int e=0;e<4;e++){
      float a = es1[mt][e], b = es2[mt][e];
      a += __shfl_xor(a,1,64); a += __shfl_xor(a,2,64);
      a += __shfl_xor(a,4,64); a += __shfl_xor(a,8,64);
      b += __shfl_xor(b,1,64); b += __shfl_xor(b,2,64);
      b += __shfl_xor(b,4,64); b += __shfl_xor(b,8,64);
      if (c == 0){
        int f = mt*16 + 4*g + e;
        atomicAdd(&sst2[f],    a);
        atomicAdd(&sst2[64+f], b);
      }
    }
  __syncthreads();
  if (threadIdx.x < 128) atomicAdd(&est[threadIdx.x], sst2[threadIdx.x]);
}

// ---- bz_k: 5:1 split. bid%6<5: node aggregation (latency-bound — gets
// ~full residency). bid%6==5: y streaming with 2-row unroll (few waves,
// high per-wave issue rate).
__global__ __launch_bounds__(256) void bz_k(
    const __bf16* __restrict__ m16, const int2* __restrict__ pairs,
    const __bf16* __restrict__ bh16, const int* __restrict__ rowp,
    const float* __restrict__ b_du, const float* __restrict__ b_su,
    float* __restrict__ A_src, float* __restrict__ nst, int Nn,
    const float* __restrict__ ef, const float* __restrict__ est,
    const float* __restrict__ ge, const float* __restrict__ bte,
    float* __restrict__ y, float invE, long E)
{
  int nb_b = (gridDim.x/6)*5;
  int nb_y = gridDim.x/6;
  int m6 = blockIdx.x % 6;
  if (m6 < 5){
    // ---- phaseB part (5/6 of blocks) ----
    __shared__ float sst[128];
    if (threadIdx.x < 128) sst[threadIdx.x] = 0.f;
    __syncthreads();
    int vb = (blockIdx.x/6)*5 + m6;
    int lane = threadIdx.x & 63, w = threadIdx.x>>6;
    float bdu = b_du[lane], bsu = b_su[lane];
    int chunk = (Nn + nb_b - 1)/nb_b;
    int n0 = vb*chunk;
    int n1 = n0 + chunk; if (n1 > Nn) n1 = Nn;
    float p1=0.f, p2=0.f;
    for (int n=n0+w; n<n1; n+=4){
      int r0 = rowp[n], r1 = rowp[n+1];
      float ssum=0.f, bsum=0.f;
      int r = r0;
      int2 q[8];
      bool have = (r + 8 <= r1);
      if (have){
        #pragma unroll
        for (int j=0;j<8;j++) q[j] = pairs[r+j];
      }
      while (have){
        int rn = r + 8;
        bool haven = (rn + 8 <= r1);
        int2 qn[8];
        if (haven){
          #pragma unroll
          for (int j=0;j<8;j++) qn[j] = pairs[rn+j];
        }
        float mv[8], bh[8];
        #pragma unroll
        for (int j=0;j<8;j++) mv[j] = (float)m16[(long)q[j].x*64 + lane];
        #pragma unroll
        for (int j=0;j<8;j++) bh[j] = (float)bh16[(long)q[j].y*64 + lane] + bdu;
        #pragma unroll
        for (int j=0;j<8;j++){
          float sg = 1.f/(1.f+__expf(-mv[j]));
          ssum += sg; bsum += bh[j]*sg;
        }
        if (haven){
          #pragma unroll
          for (int j=0;j<8;j++) q[j] = qn[j];
        }
        r = rn; have = haven;
      }
      for (; r < r1; ++r){
        int2 q0 = pairs[r];
        float mv0 = (float)m16[(long)q0.x*64 + lane];
        float bh0 = (float)bh16[(long)q0.y*64 + lane] + bdu;
        float sg0 = 1.f/(1.f+__expf(-mv0));
        ssum += sg0; bsum += bh0*sg0;
      }
      long xi = (long)n*64 + lane;
      float xp = A_src[xi] + bsu + bsum/(ssum+1e-6f);
      A_src[xi] = xp;
      p1 += xp; p2 += xp*xp;
    }
    atomicAdd(&sst[lane],    p1);
    atomicAdd(&sst[64+lane], p2);
    __syncthreads();
    if (threadIdx.x < 128) atomicAdd(&nst[threadIdx.x], sst[threadIdx.x]);
  } else {
    // ---- y-final part (1/6 of blocks, pure streaming, 2-row unroll) ----
    int oct = threadIdx.x & 7;
    float aa[8], bb[8];
    #pragma unroll
    for (int j=0;j<8;j++){
      int col = oct*8 + j;
      float mu = est[col]*invE;
      float var = est[64+col]*invE - mu*mu;
      float rs = rsqrtf(var + 1e-5f);
      float ga = ge[col]*rs;
      aa[j] = ga; bb[j] = bte[col] - mu*ga;
    }
    int vy = blockIdx.x/6;
    long tid = (long)vy*256 + threadIdx.x;
    long pstep = ((long)nb_y*256) >> 3;
    long p0 = tid>>3;
    for (long p = p0; p < E; p += 2*pstep){
      long pB = p + pstep;
      bool hasB = (pB < E);
      bf16x8 mvA = *(const bf16x8*)&m16[p*64 + oct*8];
      const float* rpA = ef + p*64 + oct*8;
      float4 fA0 = *(const float4*)rpA, fA1 = *(const float4*)(rpA+4);
      bf16x8 mvB;
      float4 fB0, fB1;
      if (hasB){
        mvB = *(const bf16x8*)&m16[pB*64 + oct*8];
        const float* rpB = ef + pB*64 + oct*8;
        fB0 = *(const float4*)rpB; fB1 = *(const float4*)(rpB+4);
      }
      float o[8];
      #pragma unroll
      for (int j=0;j<8;j++){
        float z = aa[j]*(float)mvA[j] + bb[j];
        float ev = (j<4) ? ((const float*)&fA0)[j] : ((const float*)&fA1)[j-4];
        o[j] = ev + z/(1.f+__expf(-z));
      }
      float* ypA = y + p*64 + oct*8;
      *(float4*)ypA     = make_float4(o[0],o[1],o[2],o[3]);
      *(float4*)(ypA+4) = make_float4(o[4],o[5],o[6],o[7]);
      if (hasB){
        #pragma unroll
        for (int j=0;j<8;j++){
          float z = aa[j]*(float)mvB[j] + bb[j];
          float ev = (j<4) ? ((const float*)&fB0)[j] : ((const float*)&fB1)[j-4];
          o[j] = ev + z/(1.f+__expf(-z));
        }
        float* ypB = y + pB*64 + oct*8;
        *(float4*)ypB     = make_float4(o[0],o[1],o[2],o[3]);
        *(float4*)(ypB+4) = make_float4(o[4],o[5],o[6],o[7]);
      }
    }
  }
}

// ---- x-final: x = nf + silu(bn(x_pre))
__global__ __launch_bounds__(256) void xfin_k(
    const float* __restrict__ nf, const float* __restrict__ xpre,
    const float* __restrict__ nst, const float* __restrict__ gn,
    const float* __restrict__ btn, float* __restrict__ xo, int Nn)
{
  long tid = (long)blockIdx.x*256 + threadIdx.x;
  long stride = (long)gridDim.x*256;
  int col = (int)(tid & 63);
  float invN = 1.f/(float)Nn;
  float mu = nst[col]*invN;
  float var = nst[64+col]*invN - mu*mu;
  float rs = rsqrtf(var + 1e-5f);
  float aa = gn[col]*rs;
  float bb = btn[col] - mu*aa;
  long total = (long)Nn*64;
  for (long i=tid; i<total; i+=stride){
    float z = xpre[i]*aa + bb;
    xo[i] = nf[i] + z/(1.f+__expf(-z));
  }
}

extern "C" void kernel_launch(void* const* d_in, const int* in_sizes, int n_in,
                              void* d_out, int out_size, void* d_ws, size_t ws_size,
                              hipStream_t stream){
  const float* nf  = (const float*)d_in[0];
  const float* ef  = (const float*)d_in[1];
  const int*   src = (const int*)d_in[2];
  const int*   dst = (const int*)d_in[3];
  const float* W_sg=(const float*)d_in[4];  const float* b_sg=(const float*)d_in[5];
  const float* W_dg=(const float*)d_in[6];  const float* b_dg=(const float*)d_in[7];
  const float* W_eg=(const float*)d_in[8];  const float* b_eg=(const float*)d_in[9];
  const float* W_su=(const float*)d_in[10]; const float* b_su=(const float*)d_in[11];
  const float* W_du=(const float*)d_in[12]; const float* b_du=(const float*)d_in[13];
  const float* gn=(const float*)d_in[14];   const float* btn=(const float*)d_in[15];
  const float* ge=(const float*)d_in[16];   const float* bte=(const float*)d_in[17];

  int Nn = in_sizes[0]/64;
  int Ee = in_sizes[2];
  size_t Nf = (size_t)Nn*64;
  size_t Es = (size_t)Ee;

  float* ws    = (float*)d_ws;
  float* A_src = ws;                          // Nf f32 (becomes x_pre)
  __bf16* es16 = (__bf16*)(ws + Nf);          // Nf/2 floats
  __bf16* ed16 = (__bf16*)(ws + Nf + Nf/2);   // Nf/2
  __bf16* bh16 = (__bf16*)(ws + 2*Nf);        // Nf/2
  __bf16* m16  = (__bf16*)(ws + 2*Nf + Nf/2); // 32*Es floats
  int2*  pairs = (int2*)(ws + 2*Nf + Nf/2 + 32*Es);  // 2*Es
  int*   cnt   = (int*)(pairs + Es);          // Nn
  int*   cnt2  = cnt + Nn;                    // Nn
  float* est   = (float*)(cnt2 + Nn);         // 128
  float* nst   = est + 128;                   // 128
  int*   rowp  = (int*)(nst + 128);           // Nn+1
  size_t woff  = 2*Nf + Nf/2 + 32*Es + 2*Es + 2*(size_t)Nn + 256 + (size_t)Nn + 1;
  woff = (woff + 15) & ~(size_t)15;
  bf16x8* Wq   = (bf16x8*)(ws + woff);        // 2560 frags

  float* xo = (float*)d_out;
  float* yo = xo + Nf;

  int nz4 = (int)((2*(size_t)Nn + 256) >> 2);
  setup_k<<<272,256,0,stream>>>(W_sg,W_dg,W_eg,W_su,W_du,Wq,(int4*)cnt,nz4);

  int ntn = Nn/16;
  int nxf = (ntn+3)/4;
  xform_hist_k<<<nxf+2048,256,0,stream>>>(nf,Wq,es16,ed16,bh16,A_src,ntn,nxf,
                                          dst,cnt,Ee);
  scan_k<<<1,1024,0,stream>>>(cnt,rowp,Nn);
  int nte = Ee/16;
  fillA_k<<<NFILL+4096,256,0,stream>>>(src,dst,rowp,cnt2,pairs,Ee,
                                       ef,es16,ed16,b_sg,b_dg,b_eg,Wq,m16,est,nte);
  bz_k<<<6144,256,0,stream>>>(m16,pairs,bh16,rowp,b_du,b_su,A_src,nst,Nn,
                              ef,est,ge,bte,yo,1.f/(float)Ee,(long)Ee);
  xfin_k<<<1024,256,0,stream>>>(nf,A_src,nst,gn,btn,xo,Nn);
}

// Round 19
// 827.133 us; speedup vs baseline: 1.1006x; 1.1006x over previous
//
#include <hip/hip_runtime.h>
#include <hip/hip_bf16.h>

typedef __attribute__((ext_vector_type(8))) __bf16 bf16x8;
typedef __attribute__((ext_vector_type(4))) float f32x4;

#define MFMA(a,b,c) __builtin_amdgcn_mfma_f32_16x16x32_bf16((a),(b),(c),0,0,0)

__device__ __forceinline__ bf16x8 cvt8(float4 a, float4 b){
  bf16x8 r;
  r[0]=(__bf16)a.x; r[1]=(__bf16)a.y; r[2]=(__bf16)a.z; r[3]=(__bf16)a.w;
  r[4]=(__bf16)b.x; r[5]=(__bf16)b.y; r[6]=(__bf16)b.z; r[7]=(__bf16)b.w;
  return r;
}

// ---- fused setup: blocks 0-15 pack weights (transposed A-operand layout),
// blocks 16+ zero the counter/stat region.
__global__ void setup_k(const float* __restrict__ W_sg, const float* __restrict__ W_dg,
                        const float* __restrict__ W_eg, const float* __restrict__ W_su,
                        const float* __restrict__ W_du,
                        bf16x8* __restrict__ Wq,
                        int4* __restrict__ zp, int nz4){
  if (blockIdx.x < 16){
    int tid = blockIdx.x*256 + threadIdx.x;
    if (tid >= 2560) return;
    int lane = tid & 63, g = lane>>4, c = lane&15;
    int frag = (tid>>6)&7, m = tid>>9;
    const float* Ws[5] = {W_eg, W_sg, W_dg, W_du, W_su};
    const float* W = Ws[m];
    int mt = frag>>1, kh = frag&1;
    bf16x8 v;
    #pragma unroll
    for (int j=0;j<8;j++) v[j] = (__bf16)W[(kh*32+g*8+j)*64 + mt*16 + c];
    Wq[tid] = v;
  } else {
    int i = (blockIdx.x-16)*256 + threadIdx.x, st = (gridDim.x-16)*256;
    for (; i<nz4; i+=st) zp[i] = make_int4(0,0,0,0);
  }
}

// ---- fused: blocks [0,nxf): node transforms -> es16/ed16/bh16 (bf16, no bias)
// + A_src (f32, no bias); blocks [nxf,+): dst histogram.
__global__ __launch_bounds__(256) void xform_hist_k(
    const float* __restrict__ nf, const bf16x8* __restrict__ Wq,
    __bf16* __restrict__ es16, __bf16* __restrict__ ed16,
    __bf16* __restrict__ bh16, float* __restrict__ A_src, int ntiles, int nxf,
    const int* __restrict__ dst, int* __restrict__ cnt, int E)
{
  if ((int)blockIdx.x < nxf){
    int lane = threadIdx.x & 63;
    int gw = blockIdx.x*4 + (threadIdx.x>>6);
    if (gw >= ntiles) return;
    int g = lane>>4, c = lane&15;
    long base = (long)gw*16;
    const float* rp = nf + (base + c)*64 + g*8;
    float4 a0 = *(const float4*)rp,      a1 = *(const float4*)(rp+4);
    float4 a2 = *(const float4*)(rp+32), a3 = *(const float4*)(rp+36);
    bf16x8 B0 = cvt8(a0,a1), B1 = cvt8(a2,a3);
    __bf16* outs[3] = {es16, ed16, bh16};
    const int mats[3] = {1,2,3};           // sg, dg, du
    #pragma unroll
    for (int i=0;i<3;i++){
      #pragma unroll
      for (int mt=0;mt<4;mt++){
        f32x4 am = {0.f,0.f,0.f,0.f};
        am = MFMA(Wq[(mats[i]*8+mt*2+0)*64+lane], B0, am);
        am = MFMA(Wq[(mats[i]*8+mt*2+1)*64+lane], B1, am);
        union { __bf16 h[4]; uint2 u; } pk;
        #pragma unroll
        for (int e=0;e<4;e++) pk.h[e] = (__bf16)am[e];
        *(uint2*)(outs[i] + (base+c)*64 + mt*16 + 4*g) = pk.u;
      }
    }
    #pragma unroll
    for (int mt=0;mt<4;mt++){
      f32x4 am = {0.f,0.f,0.f,0.f};
      am = MFMA(Wq[(4*8+mt*2+0)*64+lane], B0, am);
      am = MFMA(Wq[(4*8+mt*2+1)*64+lane], B1, am);
      *(float4*)(A_src + (base+c)*64 + mt*16 + 4*g) =
        make_float4(am[0],am[1],am[2],am[3]);
    }
  } else {
    int nb = gridDim.x - nxf;
    int i = (blockIdx.x-nxf)*256 + threadIdx.x, st = nb*256;
    for (; i<E; i+=st) atomicAdd(&cnt[dst[i]], 1);
  }
}

__global__ __launch_bounds__(1024) void scan_k(const int* __restrict__ cnt,
                                               int* __restrict__ row, int Nn){
  __shared__ int part[1024];
  int t = threadIdx.x;
  int C = (Nn + 1023) >> 10;
  int lo = t*C;
  int hi = lo + C; if (hi > Nn) hi = Nn;
  int s = 0;
  for (int i=lo; i<hi; i++) s += cnt[i];
  part[t] = s;
  __syncthreads();
  for (int off=1; off<1024; off<<=1){
    int v = part[t];
    int u = (t>=off) ? part[t-off] : 0;
    __syncthreads();
    part[t] = v + u;
    __syncthreads();
  }
  int excl = (t==0) ? 0 : part[t-1];
  for (int i=lo; i<hi; i++){ row[i] = excl; excl += cnt[i]; }
  if (t==1023) row[Nn] = excl;
}

struct T2 {
  float4 e0,e1,e2,e3;
  bf16x8 bs0,bs1,bd0,bd1;
};

__device__ __forceinline__ T2 ld_t2(const float* __restrict__ ef,
                                    const __bf16* __restrict__ es16,
                                    const __bf16* __restrict__ ed16,
                                    long base, int c, int g, int sc, int dc){
  T2 t;
  const float* rpe = ef + (base+c)*64 + g*8;
  t.e0=*(const float4*)rpe;      t.e1=*(const float4*)(rpe+4);
  t.e2=*(const float4*)(rpe+32); t.e3=*(const float4*)(rpe+36);
  t.bs0 = *(const bf16x8*)(es16 + (long)sc*64 + g*8);
  t.bs1 = *(const bf16x8*)(es16 + (long)sc*64 + 32 + g*8);
  t.bd0 = *(const bf16x8*)(ed16 + (long)dc*64 + g*8);
  t.bd1 = *(const bf16x8*)(ed16 + (long)dc*64 + 32 + g*8);
  return t;
}

// ---- fused: blocks [0,NFILL) CSR fill; blocks [NFILL,+) phaseA.
// phaseA: eid-major, 2-deep pipeline, LDS-staged coalesced m16 stores,
// PLUS edge-BN stat accumulation (sum m, sum m^2) -> est.
#define NFILL 1024
__global__ __launch_bounds__(256) void fillA_k(
    const int* __restrict__ src, const int* __restrict__ dst,
    const int* __restrict__ rowp, int* __restrict__ cnt2,
    int2* __restrict__ pairs, int E,
    const float* __restrict__ ef,
    const __bf16* __restrict__ es16, const __bf16* __restrict__ ed16,
    const float* __restrict__ b_sg, const float* __restrict__ b_dg,
    const float* __restrict__ b_eg,
    const bf16x8* __restrict__ Wq,
    __bf16* __restrict__ m16, float* __restrict__ est, int ntiles)
{
  __shared__ bf16x8 wl[8*64];      // W_eg^T frags (8KB)
  __shared__ uint2 mst[4][256];    // per-wave m16 tile stage (8KB)
  __shared__ float sst2[128];      // block-level est stage
  if (blockIdx.x < NFILL){
    int i = blockIdx.x*256 + threadIdx.x, st = NFILL*256;
    for (; i<E; i+=st){
      int d = dst[i];
      int pos = rowp[d] + atomicAdd(&cnt2[d], 1);
      pairs[pos] = make_int2(i, src[i]);
    }
    return;
  }
  {
    int t = threadIdx.x;
    #pragma unroll
    for (int i=0;i<2;i++) wl[i*256+t] = Wq[i*256+t];   // eg frags 0-7
    if (t < 128) sst2[t] = 0.f;
  }
  __syncthreads();
  int lane = threadIdx.x & 63, g = lane>>4, c = lane&15;
  int wv = threadIdx.x>>6;
  bf16x8 I0, I1;
  #pragma unroll
  for (int j=0;j<8;j++){
    I0[j] = (g*8+j == c)      ? (__bf16)1.0f : (__bf16)0.0f;
    I1[j] = (g*8+j == 16 + c) ? (__bf16)1.0f : (__bf16)0.0f;
  }
  int gw = (blockIdx.x-NFILL)*4 + wv;
  int nw = (gridDim.x-NFILL)*4;
  float bias2[4][4], es1[4][4], es2[4][4];
  #pragma unroll
  for (int mt=0;mt<4;mt++)
    #pragma unroll
    for (int e=0;e<4;e++){
      int f = mt*16 + 4*g + e;
      bias2[mt][e] = b_sg[f] + b_dg[f] + b_eg[f];
      es1[mt][e] = 0.f; es2[mt][e] = 0.f;
    }
  if (gw < ntiles){
    int sc = src[(long)gw*16 + c], dc = dst[(long)gw*16 + c];
    T2 cur = ld_t2(ef, es16, ed16, (long)gw*16, c, g, sc, dc);
    int t1i = gw + nw;
    int sn = sc, dn = dc;
    if (t1i < ntiles){ sn = src[(long)t1i*16 + c]; dn = dst[(long)t1i*16 + c]; }
    int r_o = lane>>3;
    int u0_o = (lane&7)*2;
    for (int tt=gw; tt<ntiles; tt+=nw){
      int t1 = tt + nw;
      T2 nxt;
      if (t1 < ntiles) nxt = ld_t2(ef, es16, ed16, (long)t1*16, c, g, sn, dn);
      int t2 = t1 + nw;
      if (t2 < ntiles){ sn = src[(long)t2*16 + c]; dn = dst[(long)t2*16 + c]; }
      bf16x8 BE0=cvt8(cur.e0,cur.e1), BE1=cvt8(cur.e2,cur.e3);
      #pragma unroll
      for (int mt=0;mt<4;mt++){
        bf16x8 Is = (mt&1) ? I1 : I0;
        f32x4 am = {0.f,0.f,0.f,0.f};
        am = MFMA(wl[(mt*2+0)*64+lane], BE0, am);
        am = MFMA(wl[(mt*2+1)*64+lane], BE1, am);
        am = MFMA(Is, (mt>>1) ? cur.bs1 : cur.bs0, am);
        am = MFMA(Is, (mt>>1) ? cur.bd1 : cur.bd0, am);
        union { __bf16 h[4]; uint2 u; } pk;
        #pragma unroll
        for (int e=0;e<4;e++){
          float mv = am[e] + bias2[mt][e];
          es1[mt][e] += mv; es2[mt][e] += mv*mv;
          pk.h[e] = (__bf16)mv;
        }
        int u = mt*4 + g;
        mst[wv][c*16 + (u^c)] = pk.u;
      }
      char* tb = (char*)m16 + (size_t)tt*16*128;
      #pragma unroll
      for (int k=0;k<2;k++){
        int r = k*8 + r_o;
        uint2 a = mst[wv][r*16 + ( u0_o      ^ r)];
        uint2 b = mst[wv][r*16 + ((u0_o + 1) ^ r)];
        *(uint4*)(tb + k*1024 + lane*16) = make_uint4(a.x,a.y,b.x,b.y);
      }
      cur = nxt;
    }
  }
  // est flush: shfl-reduce over c-groups, LDS, then global atomics
  #pragma unroll
  for (int mt=0;mt<4;mt++)
    #pragma unroll
    for (int e=0;e<4;e++){
      float a = es1[mt][e], b = es2[mt][e];
      a += __shfl_xor(a,1,64); a += __shfl_xor(a,2,64);
      a += __shfl_xor(a,4,64); a += __shfl_xor(a,8,64);
      b += __shfl_xor(b,1,64); b += __shfl_xor(b,2,64);
      b += __shfl_xor(b,4,64); b += __shfl_xor(b,8,64);
      if (c == 0){
        int f = mt*16 + 4*g + e;
        atomicAdd(&sst2[f],    a);
        atomicAdd(&sst2[64+f], b);
      }
    }
  __syncthreads();
  if (threadIdx.x < 128) atomicAdd(&est[threadIdx.x], sst2[threadIdx.x]);
}

// ---- bz_k: 2:1 split. bid%3<2 (2/3 of blocks): node aggregation — keeps
// high gather concurrency (latency-bound). bid%3==2 (1/3): y streaming.
__global__ __launch_bounds__(256) void bz_k(
    const __bf16* __restrict__ m16, const int2* __restrict__ pairs,
    const __bf16* __restrict__ bh16, const int* __restrict__ rowp,
    const float* __restrict__ b_du, const float* __restrict__ b_su,
    float* __restrict__ A_src, float* __restrict__ nst, int Nn,
    const float* __restrict__ ef, const float* __restrict__ est,
    const float* __restrict__ ge, const float* __restrict__ bte,
    float* __restrict__ y, float invE, long E)
{
  int nb_b = (gridDim.x/3)*2;
  int nb_y = gridDim.x/3;
  int m3 = blockIdx.x % 3;
  if (m3 < 2){
    // ---- phaseB part (2/3 of blocks) ----
    __shared__ float sst[128];
    if (threadIdx.x < 128) sst[threadIdx.x] = 0.f;
    __syncthreads();
    int vb = (blockIdx.x/3)*2 + m3;
    int lane = threadIdx.x & 63, w = threadIdx.x>>6;
    float bdu = b_du[lane], bsu = b_su[lane];
    int chunk = (Nn + nb_b - 1)/nb_b;
    int n0 = vb*chunk;
    int n1 = n0 + chunk; if (n1 > Nn) n1 = Nn;
    float p1=0.f, p2=0.f;
    for (int n=n0+w; n<n1; n+=4){
      int r0 = rowp[n], r1 = rowp[n+1];
      float ssum=0.f, bsum=0.f;
      int r = r0;
      for (; r+8 <= r1; r+=8){
        int2 q[8];
        #pragma unroll
        for (int j=0;j<8;j++) q[j] = pairs[r+j];
        float mv[8], bh[8];
        #pragma unroll
        for (int j=0;j<8;j++) mv[j] = (float)m16[(long)q[j].x*64 + lane];
        #pragma unroll
        for (int j=0;j<8;j++) bh[j] = (float)bh16[(long)q[j].y*64 + lane] + bdu;
        #pragma unroll
        for (int j=0;j<8;j++){
          float sg = 1.f/(1.f+__expf(-mv[j]));
          ssum += sg; bsum += bh[j]*sg;
        }
      }
      for (; r < r1; ++r){
        int2 q0 = pairs[r];
        float mv0 = (float)m16[(long)q0.x*64 + lane];
        float bh0 = (float)bh16[(long)q0.y*64 + lane] + bdu;
        float sg0 = 1.f/(1.f+__expf(-mv0));
        ssum += sg0; bsum += bh0*sg0;
      }
      long xi = (long)n*64 + lane;
      float xp = A_src[xi] + bsu + bsum/(ssum+1e-6f);
      A_src[xi] = xp;
      p1 += xp; p2 += xp*xp;
    }
    atomicAdd(&sst[lane],    p1);
    atomicAdd(&sst[64+lane], p2);
    __syncthreads();
    if (threadIdx.x < 128) atomicAdd(&nst[threadIdx.x], sst[threadIdx.x]);
  } else {
    // ---- y-final part (1/3 of blocks, pure streaming) ----
    int oct = threadIdx.x & 7;
    float aa[8], bb[8];
    #pragma unroll
    for (int j=0;j<8;j++){
      int col = oct*8 + j;
      float mu = est[col]*invE;
      float var = est[64+col]*invE - mu*mu;
      float rs = rsqrtf(var + 1e-5f);
      float ga = ge[col]*rs;
      aa[j] = ga; bb[j] = bte[col] - mu*ga;
    }
    int vy = blockIdx.x/3;
    long tid = (long)vy*256 + threadIdx.x;
    long pstep = ((long)nb_y*256) >> 3;
    for (long p = tid>>3; p < E; p += pstep){
      bf16x8 mv = *(const bf16x8*)&m16[p*64 + oct*8];
      const float* rp = ef + p*64 + oct*8;
      float4 f0 = *(const float4*)rp, f1 = *(const float4*)(rp+4);
      float o[8];
      #pragma unroll
      for (int j=0;j<8;j++){
        float z = aa[j]*(float)mv[j] + bb[j];
        float ev = (j<4) ? ((const float*)&f0)[j] : ((const float*)&f1)[j-4];
        o[j] = ev + z/(1.f+__expf(-z));
      }
      float* yp = y + p*64 + oct*8;
      *(float4*)yp     = make_float4(o[0],o[1],o[2],o[3]);
      *(float4*)(yp+4) = make_float4(o[4],o[5],o[6],o[7]);
    }
  }
}

// ---- x-final: x = nf + silu(bn(x_pre))
__global__ __launch_bounds__(256) void xfin_k(
    const float* __restrict__ nf, const float* __restrict__ xpre,
    const float* __restrict__ nst, const float* __restrict__ gn,
    const float* __restrict__ btn, float* __restrict__ xo, int Nn)
{
  long tid = (long)blockIdx.x*256 + threadIdx.x;
  long stride = (long)gridDim.x*256;
  int col = (int)(tid & 63);
  float invN = 1.f/(float)Nn;
  float mu = nst[col]*invN;
  float var = nst[64+col]*invN - mu*mu;
  float rs = rsqrtf(var + 1e-5f);
  float aa = gn[col]*rs;
  float bb = btn[col] - mu*aa;
  long total = (long)Nn*64;
  for (long i=tid; i<total; i+=stride){
    float z = xpre[i]*aa + bb;
    xo[i] = nf[i] + z/(1.f+__expf(-z));
  }
}

extern "C" void kernel_launch(void* const* d_in, const int* in_sizes, int n_in,
                              void* d_out, int out_size, void* d_ws, size_t ws_size,
                              hipStream_t stream){
  const float* nf  = (const float*)d_in[0];
  const float* ef  = (const float*)d_in[1];
  const int*   src = (const int*)d_in[2];
  const int*   dst = (const int*)d_in[3];
  const float* W_sg=(const float*)d_in[4];  const float* b_sg=(const float*)d_in[5];
  const float* W_dg=(const float*)d_in[6];  const float* b_dg=(const float*)d_in[7];
  const float* W_eg=(const float*)d_in[8];  const float* b_eg=(const float*)d_in[9];
  const float* W_su=(const float*)d_in[10]; const float* b_su=(const float*)d_in[11];
  const float* W_du=(const float*)d_in[12]; const float* b_du=(const float*)d_in[13];
  const float* gn=(const float*)d_in[14];   const float* btn=(const float*)d_in[15];
  const float* ge=(const float*)d_in[16];   const float* bte=(const float*)d_in[17];

  int Nn = in_sizes[0]/64;
  int Ee = in_sizes[2];
  size_t Nf = (size_t)Nn*64;
  size_t Es = (size_t)Ee;

  float* ws    = (float*)d_ws;
  float* A_src = ws;                          // Nf f32 (becomes x_pre)
  __bf16* es16 = (__bf16*)(ws + Nf);          // Nf/2 floats
  __bf16* ed16 = (__bf16*)(ws + Nf + Nf/2);   // Nf/2
  __bf16* bh16 = (__bf16*)(ws + 2*Nf);        // Nf/2
  __bf16* m16  = (__bf16*)(ws + 2*Nf + Nf/2); // 32*Es floats
  int2*  pairs = (int2*)(ws + 2*Nf + Nf/2 + 32*Es);  // 2*Es
  int*   cnt   = (int*)(pairs + Es);          // Nn
  int*   cnt2  = cnt + Nn;                    // Nn
  float* est   = (float*)(cnt2 + Nn);         // 128
  float* nst   = est + 128;                   // 128
  int*   rowp  = (int*)(nst + 128);           // Nn+1
  size_t woff  = 2*Nf + Nf/2 + 32*Es + 2*Es + 2*(size_t)Nn + 256 + (size_t)Nn + 1;
  woff = (woff + 15) & ~(size_t)15;
  bf16x8* Wq   = (bf16x8*)(ws + woff);        // 2560 frags

  float* xo = (float*)d_out;
  float* yo = xo + Nf;

  int nz4 = (int)((2*(size_t)Nn + 256) >> 2);
  setup_k<<<272,256,0,stream>>>(W_sg,W_dg,W_eg,W_su,W_du,Wq,(int4*)cnt,nz4);

  int ntn = Nn/16;
  int nxf = (ntn+3)/4;
  xform_hist_k<<<nxf+2048,256,0,stream>>>(nf,Wq,es16,ed16,bh16,A_src,ntn,nxf,
                                          dst,cnt,Ee);
  scan_k<<<1,1024,0,stream>>>(cnt,rowp,Nn);
  int nte = Ee/16;
  fillA_k<<<NFILL+4096,256,0,stream>>>(src,dst,rowp,cnt2,pairs,Ee,
                                       ef,es16,ed16,b_sg,b_dg,b_eg,Wq,m16,est,nte);
  bz_k<<<6144,256,0,stream>>>(m16,pairs,bh16,rowp,b_du,b_su,A_src,nst,Nn,
                              ef,est,ge,bte,yo,1.f/(float)Ee,(long)Ee);
  xfin_k<<<1024,256,0,stream>>>(nf,A_src,nst,gn,btn,xo,Nn);
}